// Round 5
// baseline (573.040 us; speedup 1.0000x reference)
//
#include <hip/hip_runtime.h>
#include <math.h>

#define NPROP 1024
#define NCLS 32
#define FEATD 4096
#define SCORE_THRESH 0.05f
#define NMS_THR 0.5f
#define PER_CLS_TOPN 300
#define DET_PER_IMG 100
#define BBOX_CLIP 4.135166556742356f   // log(1000/16)

// Compile-time-only fence for wave-synchronous LDS steps (partner in same wave):
// prevents hipcc from caching/reordering LDS accesses across the step. Same-wave
// LDS ops execute in issue order in hardware, so no s_barrier is needed.
__device__ __forceinline__ void wave_fence() {
    __builtin_amdgcn_wave_barrier();
    asm volatile("" ::: "memory");
}

// Box decode + clip for proposal n, class cls. zyxzyx, TO_REMOVE=1 convention.
// __fmul_rn/__fadd_rn block FMA contraction so coords match XLA's unfused
// mul+add (IoU>thr and score>thresh are discrete decisions). b[] is only
// indexed with compile-time constants (rule #20).
__device__ __forceinline__ void decode_box(const float* __restrict__ prop,
                                           const float* __restrict__ reg,
                                           int n, int cls, float b[6]) {
    const float lim[3] = {95.0f, 319.0f, 319.0f};
    const float* r6 = reg + n * (NCLS * 6) + cls * 6;
#pragma unroll
    for (int d = 0; d < 3; ++d) {
        float lo = prop[n * 6 + d];
        float hi = prop[n * 6 + 3 + d];
        float sz = __fadd_rn(__fsub_rn(hi, lo), 1.0f);
        float ct = __fadd_rn(lo, __fmul_rn(0.5f, sz));
        float dc = r6[d] / 10.0f;                       // W_CTR = 10
        float ds = fminf(r6[3 + d] / 5.0f, BBOX_CLIP);  // W_SIZE = 5
        float pc = __fadd_rn(__fmul_rn(dc, sz), ct);
        float ps = __fmul_rn(expf(ds), sz);
        float hps = __fmul_rn(0.5f, ps);
        float mn = __fsub_rn(pc, hps);
        float mx = __fsub_rn(__fadd_rn(pc, hps), 1.0f);
        b[d]     = fminf(fmaxf(mn, 0.0f), lim[d]);
        b[3 + d] = fminf(fmaxf(mx, 0.0f), lim[d]);
    }
}

// find first set bit >= start in a 1024-bit mask (16 u64 words); 1024 if none.
__device__ __forceinline__ int next_set(const unsigned long long* w, int start) {
    if (start >= NPROP) return NPROP;
    int wi = start >> 6;
    unsigned long long word = w[wi] & (~0ull << (start & 63));
    while (true) {
        if (word) return (wi << 6) + __ffsll((long long)word) - 1;
        if (++wi >= 16) return NPROP;
        word = w[wi];
    }
}

// ---------------- Kernel 1: fused softmax + decode + sort + NMS + top-300 ----
// grid: 31 blocks (class = blockIdx.x+1) of 1024 threads.
__global__ __launch_bounds__(1024) void nms_kernel(const float* __restrict__ logits,
                                                   const float* __restrict__ reg,
                                                   const float* __restrict__ prop,
                                                   float* __restrict__ all_scores,
                                                   int* __restrict__ all_orig) {
    const int cls = blockIdx.x + 1;   // foreground classes 1..31
    const int tid = threadIdx.x;
    const int lane = tid & 63, wid = tid >> 6;

    __shared__ float s[NPROP];
    __shared__ int   order[NPROP];
    __shared__ float sb[NPROP][6];
    __shared__ float vols[NPROP];
    __shared__ unsigned long long keepw[2][16];
    __shared__ int   wtot[16];

    // --- inline softmax for this thread's own proposal row (static indexing) ---
    const float* lrow = logits + tid * NCLS;
    float4 q[8];
#pragma unroll
    for (int r = 0; r < 8; ++r) q[r] = ((const float4*)lrow)[r];
    float m = -1e30f;
#pragma unroll
    for (int r = 0; r < 8; ++r) {
        m = fmaxf(m, fmaxf(fmaxf(q[r].x, q[r].y), fmaxf(q[r].z, q[r].w)));
    }
    float ssum = 0.0f;
#pragma unroll
    for (int r = 0; r < 8; ++r) {
        ssum += expf(q[r].x - m);
        ssum += expf(q[r].y - m);
        ssum += expf(q[r].z - m);
        ssum += expf(q[r].w - m);
    }
    float xc = lrow[cls];            // scalar load; q[cls] would spill (rule #20)
    float p = expf(xc - m) / ssum;

    s[tid] = (p > SCORE_THRESH) ? p : -1.0f;
    order[tid] = tid;
    wave_fence();   // initial writes are own-slot; first sort steps are in-wave

    // Bitonic sort, descending by score, ties -> ascending original index
    // (replicates stable jnp.argsort(-s)). Steps with j<64 exchange within one
    // 64-lane wave: no s_barrier needed (in-wave LDS ordering), only wave_fence.
    for (int k = 2; k <= NPROP; k <<= 1) {
        if (k >= 128) __syncthreads();   // make prior in-wave writes visible
        for (int j = k >> 1; j > 0; j >>= 1) {
            int ixj = tid ^ j;
            if (ixj > tid) {
                float s0 = s[tid], s1 = s[ixj];
                int   i0 = order[tid], i1 = order[ixj];
                // "elem@tid comes after elem@ixj" in the desired descending order
                bool after = (s0 < s1) || (s0 == s1 && i0 > i1);
                bool dir = ((tid & k) == 0);
                if (after == dir) {
                    s[tid] = s1; s[ixj] = s0;
                    order[tid] = i1; order[ixj] = i0;
                }
            }
            if (j >= 64) __syncthreads();
            else wave_fence();
        }
    }
    __syncthreads();   // sorted arrays visible to all waves

    // Decode this thread's sorted box inline; stage to LDS
    int o = order[tid];
    float myb[6];
    decode_box(prop, reg, o, cls, myb);
#pragma unroll
    for (int d = 0; d < 6; ++d) sb[tid][d] = myb[d];
    float myvol = 1.0f;
#pragma unroll
    for (int d = 0; d < 3; ++d)
        myvol *= fmaxf(myb[3 + d] - myb[d] + 1.0f, 0.0f);
    vols[tid] = myvol;

    float sv = s[tid];
    int mykeep = (sv > SCORE_THRESH) ? 1 : 0;
    unsigned long long m0 = __ballot(mykeep);
    if (lane == 0) keepw[0][wid] = m0;
    __syncthreads();

    // Greedy NMS: iterate ONLY over kept candidates (skipped i's are exactly
    // the reference iterations whose body is a no-op). keep status mirrored in
    // a ping-pong 1024-bit LDS mask rebuilt by ballot each round.
    int parity = 0;
    int i = next_set(keepw[0], 0);
    while (i < NPROP) {
        if (mykeep && tid > i) {
            float inter = 1.0f;
#pragma unroll
            for (int d = 0; d < 3; ++d) {
                float lt = fmaxf(sb[i][d], myb[d]);
                float rb = fminf(sb[i][3 + d], myb[3 + d]);
                inter *= fmaxf(rb - lt + 1.0f, 0.0f);
            }
            float denom = vols[i] + myvol - inter + 1e-12f;
            if (inter / denom > NMS_THR) mykeep = 0;
        }
        unsigned long long mm = __ballot(mykeep);
        if (lane == 0) keepw[parity ^ 1][wid] = mm;
        __syncthreads();
        parity ^= 1;
        i = next_set(keepw[parity], i + 1);
    }

    // rank = exclusive prefix count of keep; keep only rank < 300
    unsigned long long mask = __ballot(mykeep);
    int pre = __popcll(mask & ((1ull << lane) - 1ull));
    if (lane == 0) wtot[wid] = __popcll(mask);
    __syncthreads();
    int before = 0;
    for (int w = 0; w < wid; ++w) before += wtot[w];
    int rank = before + pre;
    int kf = mykeep && (rank < PER_CLS_TOPN);

    all_scores[(cls - 1) * NPROP + tid] = kf ? sv : -1.0f;
    all_orig[(cls - 1) * NPROP + tid] = order[tid];
}

// ---------------- Kernel 2: global top-100 (iterative argmax) ----------------
// 1 block of 1024 threads; element flat = t*1024 + tid lives in v[t].
// v[] only ever statically indexed (rule #20); removals via register bitmask.
// One barrier per iteration: wave leaders write parity-buffered slots, then
// every thread redundantly reduces the 16 slots (no second barrier).
__global__ __launch_bounds__(1024) void topk_kernel(const float* __restrict__ all_scores,
                                                    float* __restrict__ tk_score,
                                                    int* __restrict__ tk_idx) {
    const int tid = threadIdx.x;
    const int lane = tid & 63, wid = tid >> 6;
    float v[31];
#pragma unroll
    for (int t = 0; t < 31; ++t) v[t] = all_scores[t * NPROP + tid];
    unsigned rem = 0;   // bit t set => v[t] already emitted

    __shared__ float rv[2][16];
    __shared__ int   ri[2][16];

    int p = 0;
    for (int it = 0; it < DET_PER_IMG; ++it) {
        float bv = -1e30f;
        int bi = 0x7fffffff;
#pragma unroll
        for (int t = 0; t < 31; ++t) {
            float cand = (rem & (1u << t)) ? -1e30f : v[t];
            int flat = t * NPROP + tid;
            if (cand > bv || (cand == bv && flat < bi)) { bv = cand; bi = flat; }
        }
        // wave-level argmax (tie -> lower flat index)
#pragma unroll
        for (int off = 1; off < 64; off <<= 1) {
            float ov = __shfl_xor(bv, off);
            int   oi = __shfl_xor(bi, off);
            if (ov > bv || (ov == bv && oi < bi)) { bv = ov; bi = oi; }
        }
        if (lane == 0) { rv[p][wid] = bv; ri[p][wid] = bi; }
        __syncthreads();
        // redundant 16-way final argmax in every thread
        float fbv = rv[p][0];
        int   fbi = ri[p][0];
#pragma unroll
        for (int w = 1; w < 16; ++w) {
            float ov = rv[p][w];
            int   oi = ri[p][w];
            if (ov > fbv || (ov == fbv && oi < fbi)) { fbv = ov; fbi = oi; }
        }
        if (tid == 0) { tk_score[it] = fbv; tk_idx[it] = fbi; }
        if ((fbi & (NPROP - 1)) == tid) rem |= 1u << (fbi >> 10);  // remove winner
        p ^= 1;
    }
}

// ---------------- Kernel 3: gather outputs ----------------
// grid: DET_PER_IMG blocks of 256. Output layout (all float32):
// [100*4096 feats][100*6 boxes][100 scores][100 labels][100 valid]
__global__ void gather_kernel(const float* __restrict__ features,
                              const float* __restrict__ prop,
                              const float* __restrict__ reg,
                              const int* __restrict__ all_orig,
                              const float* __restrict__ tk_score,
                              const int* __restrict__ tk_idx,
                              float* __restrict__ out) {
    const int k = blockIdx.x;
    const int tid = threadIdx.x;
    float sc = tk_score[k];
    int flat = tk_idx[k];
    bool valid = sc > 0.0f;
    int j = flat >> 10;           // class-1
    int cls = j + 1;
    int orig = all_orig[flat];

    // features row: 4096 floats = 1024 float4, vectorized copy
    const float4* src = (const float4*)(features + (size_t)orig * FEATD);
    float4* dstf = (float4*)(out + (size_t)k * FEATD);
    const float4 z4 = make_float4(0.f, 0.f, 0.f, 0.f);
#pragma unroll
    for (int t = 0; t < 4; ++t) {
        int idx = tid + t * 256;
        dstf[idx] = valid ? src[idx] : z4;
    }

    const size_t boxOff = (size_t)DET_PER_IMG * FEATD;
    if (tid == 0) {
        float bb[6];
        decode_box(prop, reg, orig, cls, bb);   // bit-equivalent re-decode
#pragma unroll
        for (int d = 0; d < 6; ++d)
            out[boxOff + k * 6 + d] = valid ? bb[d] : 0.0f;
    }
    if (tid == 1) out[boxOff + 600 + k] = valid ? sc : 0.0f;
    if (tid == 2) out[boxOff + 700 + k] = valid ? (float)cls : 0.0f;
    if (tid == 3) out[boxOff + 800 + k] = valid ? 1.0f : 0.0f;
}

extern "C" void kernel_launch(void* const* d_in, const int* in_sizes, int n_in,
                              void* d_out, int out_size, void* d_ws, size_t ws_size,
                              hipStream_t stream) {
    (void)in_sizes; (void)n_in; (void)out_size; (void)ws_size;
    const float* features = (const float*)d_in[0];   // [1024,4096]
    const float* logits   = (const float*)d_in[1];   // [1024,32]
    const float* reg      = (const float*)d_in[2];   // [1024,192]
    const float* prop     = (const float*)d_in[3];   // [1024,6]
    float* out = (float*)d_out;

    // workspace layout (floats/ints, all 4-byte aligned)
    float* all_scores = (float*)d_ws;                    // 31744
    int*   all_orig   = (int*)(all_scores + 31 * NPROP); // 31744
    float* tk_score   = (float*)(all_orig + 31 * NPROP); // 100
    int*   tk_idx     = (int*)(tk_score + DET_PER_IMG);  // 100

    nms_kernel<<<NCLS - 1, 1024, 0, stream>>>(logits, reg, prop, all_scores, all_orig);
    topk_kernel<<<1, 1024, 0, stream>>>(all_scores, tk_score, tk_idx);
    gather_kernel<<<DET_PER_IMG, 256, 0, stream>>>(
        features, prop, reg, all_orig, tk_score, tk_idx, out);
}

// Round 6
// 256.198 us; speedup vs baseline: 2.2367x; 2.2367x over previous
//
#include <hip/hip_runtime.h>
#include <math.h>

#define NPROP 1024
#define NCLS 32
#define FEATD 4096
#define SCORE_THRESH 0.05f
#define NMS_THR 0.5f
#define PER_CLS_TOPN 300
#define DET_PER_IMG 100
#define BBOX_CLIP 4.135166556742356f   // log(1000/16)

// Compile-time-only fence for wave-synchronous LDS steps (partner in same wave):
// prevents hipcc from caching/reordering LDS accesses across the step. Same-wave
// LDS ops execute in issue order in hardware, so no s_barrier is needed.
__device__ __forceinline__ void wave_fence() {
    __builtin_amdgcn_wave_barrier();
    asm volatile("" ::: "memory");
}

// Box decode + clip for proposal n, class cls. zyxzyx, TO_REMOVE=1 convention.
// __fmul_rn/__fadd_rn block FMA contraction so coords match XLA's unfused
// mul+add (IoU>thr and score>thresh are discrete decisions). b[] is only
// indexed with compile-time constants (rule #20).
__device__ __forceinline__ void decode_box(const float* __restrict__ prop,
                                           const float* __restrict__ reg,
                                           int n, int cls, float b[6]) {
    const float lim[3] = {95.0f, 319.0f, 319.0f};
    const float* r6 = reg + n * (NCLS * 6) + cls * 6;
#pragma unroll
    for (int d = 0; d < 3; ++d) {
        float lo = prop[n * 6 + d];
        float hi = prop[n * 6 + 3 + d];
        float sz = __fadd_rn(__fsub_rn(hi, lo), 1.0f);
        float ct = __fadd_rn(lo, __fmul_rn(0.5f, sz));
        float dc = r6[d] / 10.0f;                       // W_CTR = 10
        float ds = fminf(r6[3 + d] / 5.0f, BBOX_CLIP);  // W_SIZE = 5
        float pc = __fadd_rn(__fmul_rn(dc, sz), ct);
        float ps = __fmul_rn(expf(ds), sz);
        float hps = __fmul_rn(0.5f, ps);
        float mn = __fsub_rn(pc, hps);
        float mx = __fsub_rn(__fadd_rn(pc, hps), 1.0f);
        b[d]     = fminf(fmaxf(mn, 0.0f), lim[d]);
        b[3 + d] = fminf(fmaxf(mx, 0.0f), lim[d]);
    }
}

// find first set bit >= start in a 1024-bit mask (16 u64 words); 1024 if none.
__device__ __forceinline__ int next_set(const unsigned long long* w, int start) {
    if (start >= NPROP) return NPROP;
    int wi = start >> 6;
    unsigned long long word = w[wi] & (~0ull << (start & 63));
    while (true) {
        if (word) return (wi << 6) + __ffsll((long long)word) - 1;
        if (++wi >= 16) return NPROP;
        word = w[wi];
    }
}

__device__ __forceinline__ unsigned long long u64max(unsigned long long a,
                                                     unsigned long long b) {
    return a > b ? a : b;
}

// ---------------- Kernel 1: fused softmax + decode + sort + NMS + top-300 ----
// grid: 31 blocks (class = blockIdx.x+1) of 1024 threads.
__global__ __launch_bounds__(1024) void nms_kernel(const float* __restrict__ logits,
                                                   const float* __restrict__ reg,
                                                   const float* __restrict__ prop,
                                                   float* __restrict__ all_scores,
                                                   int* __restrict__ all_orig) {
    const int cls = blockIdx.x + 1;   // foreground classes 1..31
    const int tid = threadIdx.x;
    const int lane = tid & 63, wid = tid >> 6;

    __shared__ float s[NPROP];
    __shared__ int   order[NPROP];
    __shared__ float sb[NPROP][6];
    __shared__ float vols[NPROP];
    __shared__ unsigned long long keepw[2][16];
    __shared__ int   wtot[16];

    // --- inline softmax for this thread's own proposal row (static indexing) ---
    const float* lrow = logits + tid * NCLS;
    float4 q[8];
#pragma unroll
    for (int r = 0; r < 8; ++r) q[r] = ((const float4*)lrow)[r];
    float m = -1e30f;
#pragma unroll
    for (int r = 0; r < 8; ++r) {
        m = fmaxf(m, fmaxf(fmaxf(q[r].x, q[r].y), fmaxf(q[r].z, q[r].w)));
    }
    float ssum = 0.0f;
#pragma unroll
    for (int r = 0; r < 8; ++r) {
        ssum += expf(q[r].x - m);
        ssum += expf(q[r].y - m);
        ssum += expf(q[r].z - m);
        ssum += expf(q[r].w - m);
    }
    float xc = lrow[cls];            // scalar load; q[cls] would spill (rule #20)
    float p = expf(xc - m) / ssum;

    s[tid] = (p > SCORE_THRESH) ? p : -1.0f;
    order[tid] = tid;
    wave_fence();   // initial writes are own-slot; first sort steps are in-wave

    // Bitonic sort, descending by score, ties -> ascending original index
    // (replicates stable jnp.argsort(-s)). Steps with j<64 exchange within one
    // 64-lane wave: no s_barrier needed (in-wave LDS ordering), only wave_fence.
    for (int k = 2; k <= NPROP; k <<= 1) {
        if (k >= 128) __syncthreads();   // make prior in-wave writes visible
        for (int j = k >> 1; j > 0; j >>= 1) {
            int ixj = tid ^ j;
            if (ixj > tid) {
                float s0 = s[tid], s1 = s[ixj];
                int   i0 = order[tid], i1 = order[ixj];
                // "elem@tid comes after elem@ixj" in the desired descending order
                bool after = (s0 < s1) || (s0 == s1 && i0 > i1);
                bool dir = ((tid & k) == 0);
                if (after == dir) {
                    s[tid] = s1; s[ixj] = s0;
                    order[tid] = i1; order[ixj] = i0;
                }
            }
            if (j >= 64) __syncthreads();
            else wave_fence();
        }
    }
    __syncthreads();   // sorted arrays visible to all waves

    // Decode this thread's sorted box inline; stage to LDS
    int o = order[tid];
    float myb[6];
    decode_box(prop, reg, o, cls, myb);
#pragma unroll
    for (int d = 0; d < 6; ++d) sb[tid][d] = myb[d];
    float myvol = 1.0f;
#pragma unroll
    for (int d = 0; d < 3; ++d)
        myvol *= fmaxf(myb[3 + d] - myb[d] + 1.0f, 0.0f);
    vols[tid] = myvol;

    float sv = s[tid];
    int mykeep = (sv > SCORE_THRESH) ? 1 : 0;
    unsigned long long m0 = __ballot(mykeep);
    if (lane == 0) keepw[0][wid] = m0;
    __syncthreads();

    // Greedy NMS: iterate ONLY over kept candidates (skipped i's are exactly
    // the reference iterations whose body is a no-op). keep status mirrored in
    // a ping-pong 1024-bit LDS mask rebuilt by ballot each round.
    int parity = 0;
    int i = next_set(keepw[0], 0);
    while (i < NPROP) {
        if (mykeep && tid > i) {
            float inter = 1.0f;
#pragma unroll
            for (int d = 0; d < 3; ++d) {
                float lt = fmaxf(sb[i][d], myb[d]);
                float rb = fminf(sb[i][3 + d], myb[3 + d]);
                inter *= fmaxf(rb - lt + 1.0f, 0.0f);
            }
            float denom = vols[i] + myvol - inter + 1e-12f;
            if (inter / denom > NMS_THR) mykeep = 0;
        }
        unsigned long long mm = __ballot(mykeep);
        if (lane == 0) keepw[parity ^ 1][wid] = mm;
        __syncthreads();
        parity ^= 1;
        i = next_set(keepw[parity], i + 1);
    }

    // rank = exclusive prefix count of keep; keep only rank < 300
    unsigned long long mask = __ballot(mykeep);
    int pre = __popcll(mask & ((1ull << lane) - 1ull));
    if (lane == 0) wtot[wid] = __popcll(mask);
    __syncthreads();
    int before = 0;
    for (int w = 0; w < wid; ++w) before += wtot[w];
    int rank = before + pre;
    int kf = mykeep && (rank < PER_CLS_TOPN);

    all_scores[(cls - 1) * NPROP + tid] = kf ? sv : -1.0f;
    all_orig[(cls - 1) * NPROP + tid] = order[tid];
}

// ---------------- Kernel 2: global top-100 (lazy iterative argmax) ----------
// 1 block of 1024 threads; element flat = t*1024 + tid lives in key k[t].
// Key = order-preserving u64: hi32 = monotone float flip, lo32 = ~flat, so
// u64max == (score desc, flat idx asc) — exact lax.top_k tie semantics.
// Lazy rescan: per iteration only the winner's thread rescans its 31 and only
// the winner's wave re-reduces; all other per-thread/per-wave bests are
// unchanged. One barrier per iteration via parity-buffered 16 slots.
__global__ __launch_bounds__(1024) void topk_kernel(const float* __restrict__ all_scores,
                                                    float* __restrict__ tk_score,
                                                    int* __restrict__ tk_idx) {
    const int tid = threadIdx.x;
    const int lane = tid & 63, wid = tid >> 6;

    // load + pack 31 candidates (statically indexed only — rule #20)
    unsigned long long k[31];
#pragma unroll
    for (int t = 0; t < 31; ++t) {
        float f = all_scores[t * NPROP + tid];
        unsigned u = __float_as_uint(f);
        u ^= (unsigned)(((int)u >> 31)) | 0x80000000u;   // monotone float->uint
        unsigned flat = (unsigned)(t * NPROP + tid);
        k[t] = ((unsigned long long)u << 32) | (unsigned)(~flat);
    }
    unsigned rem = 0;           // bit t set => k[t] already emitted

    unsigned long long best = 0;   // 0 < any real key (lo32 = ~flat != 0)
#pragma unroll
    for (int t = 0; t < 31; ++t) best = u64max(best, k[t]);

    // wave-level reduce of per-thread bests
    unsigned long long wb = best;
#pragma unroll
    for (int off = 1; off < 64; off <<= 1)
        wb = u64max(wb, (unsigned long long)__shfl_xor((long long)wb, off));

    __shared__ unsigned long long slot[2][16];
    if (lane == 0) slot[0][wid] = wb;
    __syncthreads();

    int p = 0;
    for (int it = 0; it < DET_PER_IMG; ++it) {
        // depth-4 max tree over the 16 wave slots (loads independent)
        unsigned long long s0 = slot[p][0],  s1 = slot[p][1];
        unsigned long long s2 = slot[p][2],  s3 = slot[p][3];
        unsigned long long s4 = slot[p][4],  s5 = slot[p][5];
        unsigned long long s6 = slot[p][6],  s7 = slot[p][7];
        unsigned long long s8 = slot[p][8],  s9 = slot[p][9];
        unsigned long long sa = slot[p][10], sb = slot[p][11];
        unsigned long long sc = slot[p][12], sd = slot[p][13];
        unsigned long long se = slot[p][14], sf = slot[p][15];
        unsigned long long w0 = u64max(u64max(s0, s1), u64max(s2, s3));
        unsigned long long w1 = u64max(u64max(s4, s5), u64max(s6, s7));
        unsigned long long w2 = u64max(u64max(s8, s9), u64max(sa, sb));
        unsigned long long w3 = u64max(u64max(sc, sd), u64max(se, sf));
        unsigned long long win = u64max(u64max(w0, w1), u64max(w2, w3));

        unsigned flat = ~(unsigned)win;                  // winner flat index
        if (tid == 0) {
            unsigned u = (unsigned)(win >> 32);          // inverse monotone map
            u = (u & 0x80000000u) ? (u ^ 0x80000000u) : ~u;
            tk_score[it] = __uint_as_float(u);
            tk_idx[it] = (int)flat;
        }

        // lazy update: only winner's thread rescans, only its wave re-reduces
        int owner = (int)(flat & (NPROP - 1));
        if (owner == tid) {
            rem |= 1u << (flat >> 10);
            best = 0;
#pragma unroll
            for (int t = 0; t < 31; ++t) {
                unsigned long long c = (rem & (1u << t)) ? 0ull : k[t];
                best = u64max(best, c);
            }
        }
        if ((owner >> 6) == wid) {
            wb = best;
#pragma unroll
            for (int off = 1; off < 64; off <<= 1)
                wb = u64max(wb, (unsigned long long)__shfl_xor((long long)wb, off));
        }
        if (lane == 0) slot[p ^ 1][wid] = wb;
        __syncthreads();
        p ^= 1;
    }
}

// ---------------- Kernel 3: gather outputs ----------------
// grid: DET_PER_IMG blocks of 256. Output layout (all float32):
// [100*4096 feats][100*6 boxes][100 scores][100 labels][100 valid]
__global__ void gather_kernel(const float* __restrict__ features,
                              const float* __restrict__ prop,
                              const float* __restrict__ reg,
                              const int* __restrict__ all_orig,
                              const float* __restrict__ tk_score,
                              const int* __restrict__ tk_idx,
                              float* __restrict__ out) {
    const int k = blockIdx.x;
    const int tid = threadIdx.x;
    float sc = tk_score[k];
    int flat = tk_idx[k];
    bool valid = sc > 0.0f;
    int j = flat >> 10;           // class-1
    int cls = j + 1;
    int orig = all_orig[flat];

    // features row: 4096 floats = 1024 float4, vectorized copy
    const float4* src = (const float4*)(features + (size_t)orig * FEATD);
    float4* dstf = (float4*)(out + (size_t)k * FEATD);
    const float4 z4 = make_float4(0.f, 0.f, 0.f, 0.f);
#pragma unroll
    for (int t = 0; t < 4; ++t) {
        int idx = tid + t * 256;
        dstf[idx] = valid ? src[idx] : z4;
    }

    const size_t boxOff = (size_t)DET_PER_IMG * FEATD;
    if (tid == 0) {
        float bb[6];
        decode_box(prop, reg, orig, cls, bb);   // bit-equivalent re-decode
#pragma unroll
        for (int d = 0; d < 6; ++d)
            out[boxOff + k * 6 + d] = valid ? bb[d] : 0.0f;
    }
    if (tid == 1) out[boxOff + 600 + k] = valid ? sc : 0.0f;
    if (tid == 2) out[boxOff + 700 + k] = valid ? (float)cls : 0.0f;
    if (tid == 3) out[boxOff + 800 + k] = valid ? 1.0f : 0.0f;
}

extern "C" void kernel_launch(void* const* d_in, const int* in_sizes, int n_in,
                              void* d_out, int out_size, void* d_ws, size_t ws_size,
                              hipStream_t stream) {
    (void)in_sizes; (void)n_in; (void)out_size; (void)ws_size;
    const float* features = (const float*)d_in[0];   // [1024,4096]
    const float* logits   = (const float*)d_in[1];   // [1024,32]
    const float* reg      = (const float*)d_in[2];   // [1024,192]
    const float* prop     = (const float*)d_in[3];   // [1024,6]
    float* out = (float*)d_out;

    // workspace layout (floats/ints, all 4-byte aligned)
    float* all_scores = (float*)d_ws;                    // 31744
    int*   all_orig   = (int*)(all_scores + 31 * NPROP); // 31744
    float* tk_score   = (float*)(all_orig + 31 * NPROP); // 100
    int*   tk_idx     = (int*)(tk_score + DET_PER_IMG);  // 100

    nms_kernel<<<NCLS - 1, 1024, 0, stream>>>(logits, reg, prop, all_scores, all_orig);
    topk_kernel<<<1, 1024, 0, stream>>>(all_scores, tk_score, tk_idx);
    gather_kernel<<<DET_PER_IMG, 256, 0, stream>>>(
        features, prop, reg, all_orig, tk_score, tk_idx, out);
}

// Round 9
// 176.354 us; speedup vs baseline: 3.2494x; 1.4527x over previous
//
#include <hip/hip_runtime.h>
#include <math.h>

#define NPROP 1024
#define NCLS 32
#define FEATD 4096
#define SCORE_THRESH 0.05f
#define NMS_THR 0.5f
#define DET_PER_IMG 100
#define CLS_STRIDE 128            // per-class compacted list stride (>=100)
#define BBOX_CLIP 4.135166556742356f   // log(1000/16)

// Compile-time-only fence for wave-synchronous LDS steps (partner in same wave):
// prevents hipcc from caching/reordering LDS accesses across the step. Same-wave
// LDS ops execute in issue order in hardware, so no s_barrier is needed.
__device__ __forceinline__ void wave_fence() {
    __builtin_amdgcn_wave_barrier();
    asm volatile("" ::: "memory");
}

__device__ __forceinline__ unsigned long long u64max(unsigned long long a,
                                                     unsigned long long b) {
    return a > b ? a : b;
}

// Box decode + clip for proposal n, class cls. zyxzyx, TO_REMOVE=1 convention.
// __fmul_rn/__fadd_rn block FMA contraction so coords match XLA's unfused
// mul+add (IoU>thr and score>thresh are discrete decisions). b[] is only
// indexed with compile-time constants (rule #20).
__device__ __forceinline__ void decode_box(const float* __restrict__ prop,
                                           const float* __restrict__ reg,
                                           int n, int cls, float b[6]) {
    const float lim[3] = {95.0f, 319.0f, 319.0f};
    const float* r6 = reg + n * (NCLS * 6) + cls * 6;
#pragma unroll
    for (int d = 0; d < 3; ++d) {
        float lo = prop[n * 6 + d];
        float hi = prop[n * 6 + 3 + d];
        float sz = __fadd_rn(__fsub_rn(hi, lo), 1.0f);
        float ct = __fadd_rn(lo, __fmul_rn(0.5f, sz));
        float dc = r6[d] / 10.0f;                       // W_CTR = 10
        float ds = fminf(r6[3 + d] / 5.0f, BBOX_CLIP);  // W_SIZE = 5
        float pc = __fadd_rn(__fmul_rn(dc, sz), ct);
        float ps = __fmul_rn(expf(ds), sz);
        float hps = __fmul_rn(0.5f, ps);
        float mn = __fsub_rn(pc, hps);
        float mx = __fsub_rn(__fadd_rn(pc, hps), 1.0f);
        b[d]     = fminf(fmaxf(mn, 0.0f), lim[d]);
        b[3 + d] = fminf(fmaxf(mx, 0.0f), lim[d]);
    }
}

// ---------------- Kernel 1: softmax + decode + sort + windowed NMS ----------
// grid: 31 blocks (class = blockIdx.x+1) of 1024 threads.
// Emits per-class compacted sorted kept list (rank<100) + count.
__global__ __launch_bounds__(1024) void nms_kernel(const float* __restrict__ logits,
                                                   const float* __restrict__ reg,
                                                   const float* __restrict__ prop,
                                                   float* __restrict__ scores_c,
                                                   int* __restrict__ orig_c,
                                                   int* __restrict__ counts) {
    const int cls = blockIdx.x + 1;   // foreground classes 1..31
    const int tid = threadIdx.x;
    const int lane = tid & 63, wid = tid >> 6;

    __shared__ float s[NPROP];
    __shared__ int   order[NPROP];
    __shared__ float sb[NPROP][6];
    __shared__ float vols[NPROP];
    __shared__ unsigned long long keepw[16];
    __shared__ int   wtot[16];
    __shared__ int   kept_cum[2];   // parity-buffered running kept count

    // --- inline softmax for this thread's own proposal row (static indexing) ---
    const float* lrow = logits + tid * NCLS;
    float4 q[8];
#pragma unroll
    for (int r = 0; r < 8; ++r) q[r] = ((const float4*)lrow)[r];
    float m = -1e30f;
#pragma unroll
    for (int r = 0; r < 8; ++r)
        m = fmaxf(m, fmaxf(fmaxf(q[r].x, q[r].y), fmaxf(q[r].z, q[r].w)));
    float ssum = 0.0f;
#pragma unroll
    for (int r = 0; r < 8; ++r) {
        ssum += expf(q[r].x - m);
        ssum += expf(q[r].y - m);
        ssum += expf(q[r].z - m);
        ssum += expf(q[r].w - m);
    }
    float xc = lrow[cls];            // scalar load; q[cls] would spill (rule #20)
    float p = expf(xc - m) / ssum;

    s[tid] = (p > SCORE_THRESH) ? p : -1.0f;
    order[tid] = tid;
    wave_fence();   // initial writes are own-slot; first sort steps are in-wave

    // Bitonic sort, descending by score, ties -> ascending original index
    // (replicates stable jnp.argsort(-s)). Steps with j<64 exchange within one
    // 64-lane wave: no s_barrier needed (in-wave LDS ordering), only wave_fence.
    for (int k = 2; k <= NPROP; k <<= 1) {
        if (k >= 128) __syncthreads();   // make prior in-wave writes visible
        for (int j = k >> 1; j > 0; j >>= 1) {
            int ixj = tid ^ j;
            if (ixj > tid) {
                float s0 = s[tid], s1 = s[ixj];
                int   i0 = order[tid], i1 = order[ixj];
                bool after = (s0 < s1) || (s0 == s1 && i0 > i1);
                bool dir = ((tid & k) == 0);
                if (after == dir) {
                    s[tid] = s1; s[ixj] = s0;
                    order[tid] = i1; order[ixj] = i0;
                }
            }
            if (j >= 64) __syncthreads();
            else wave_fence();
        }
    }
    __syncthreads();   // sorted arrays visible to all waves

    // Decode this thread's sorted box inline; stage to LDS
    int o = order[tid];
    float myb[6];
    decode_box(prop, reg, o, cls, myb);
#pragma unroll
    for (int d = 0; d < 6; ++d) sb[tid][d] = myb[d];
    float myvol = 1.0f;
#pragma unroll
    for (int d = 0; d < 3; ++d)
        myvol *= fmaxf(myb[3 + d] - myb[d] + 1.0f, 0.0f);
    vols[tid] = myvol;

    float sv = s[tid];
    int mykeep = (sv > SCORE_THRESH) ? 1 : 0;
    unsigned long long m0 = __ballot(mykeep);
    if (lane == 0) keepw[wid] = m0;
    if (tid == 0) { kept_cum[0] = 0; kept_cum[1] = 0; }
    __syncthreads();

    // Windowed greedy NMS: 16 windows of 64 sorted boxes. Each round, every
    // wave with wid>=w redundantly resolves window w's intra-window greedy
    // suppression in-register (identical result in all waves), then applies
    // the window's final kept set to its own later boxes. One barrier/round.
    // Early-stop once >=100 kept (later kept boxes get rank>=100, never
    // emitted; suppression only flows forward so earlier ranks are final).
    for (int w = 0; w < 16; ++w) {
        if (kept_cum[w & 1] >= DET_PER_IMG) break;   // uniform (post-barrier)
        unsigned long long wk = 0;
        if (wid >= w) {
            wk = keepw[w];
            const int base = w << 6;
            if (wk) {
                // my lane's window box (banks: stride 6 -> 2-way alias, free)
                float w0 = sb[base + lane][0], w1 = sb[base + lane][1];
                float w2 = sb[base + lane][2], w3 = sb[base + lane][3];
                float w4 = sb[base + lane][4], w5 = sb[base + lane][5];
                float wv = vols[base + lane];
                unsigned long long rest = wk;
                while (rest) {
                    int b = __ffsll((long long)rest) - 1;
                    rest &= rest - 1;
                    float b0 = sb[base + b][0], b1 = sb[base + b][1];
                    float b2 = sb[base + b][2], b3 = sb[base + b][3];
                    float b4 = sb[base + b][4], b5 = sb[base + b][5];
                    float bv = vols[base + b];
                    bool sup = false;
                    if (lane > b && ((wk >> lane) & 1)) {
                        float i0 = fmaxf(fminf(w3, b3) - fmaxf(w0, b0) + 1.0f, 0.0f);
                        float i1 = fmaxf(fminf(w4, b4) - fmaxf(w1, b1) + 1.0f, 0.0f);
                        float i2 = fmaxf(fminf(w5, b5) - fmaxf(w2, b2) + 1.0f, 0.0f);
                        float inter = i0 * i1 * i2;
                        sup = inter / (bv + wv - inter + 1e-12f) > NMS_THR;
                    }
                    unsigned long long supm = __ballot(sup);
                    wk &= ~supm;
                    rest &= ~supm;
                }
                if (wid == w) {
                    mykeep = (int)((wk >> lane) & 1);
                } else if (mykeep) {
                    // apply window's kept set to my (later) box
                    unsigned long long t = wk;
                    while (t) {
                        int bb = __ffsll((long long)t) - 1;
                        t &= t - 1;
                        float b0 = sb[base + bb][0], b1 = sb[base + bb][1];
                        float b2 = sb[base + bb][2], b3 = sb[base + bb][3];
                        float b4 = sb[base + bb][4], b5 = sb[base + bb][5];
                        float bv = vols[base + bb];
                        float i0 = fmaxf(fminf(myb[3], b3) - fmaxf(myb[0], b0) + 1.0f, 0.0f);
                        float i1 = fmaxf(fminf(myb[4], b4) - fmaxf(myb[1], b1) + 1.0f, 0.0f);
                        float i2 = fmaxf(fminf(myb[5], b5) - fmaxf(myb[2], b2) + 1.0f, 0.0f);
                        float inter = i0 * i1 * i2;
                        if (inter / (bv + myvol - inter + 1e-12f) > NMS_THR) {
                            mykeep = 0;
                            break;
                        }
                    }
                }
            }
            if (wid == w && lane == 0)
                kept_cum[(w + 1) & 1] = kept_cum[w & 1] + __popcll(wk);
        }
        unsigned long long mm = __ballot(mykeep);
        if (lane == 0) keepw[wid] = mm;
        __syncthreads();
    }

    // rank = exclusive prefix count of keep; emit rank < 100 compacted
    unsigned long long mask = __ballot(mykeep);
    int pre = __popcll(mask & ((1ull << lane) - 1ull));
    if (lane == 0) wtot[wid] = __popcll(mask);
    __syncthreads();
    int before = 0;
    for (int w = 0; w < wid; ++w) before += wtot[w];
    int rank = before + pre;

    if (mykeep && rank < DET_PER_IMG) {
        scores_c[(cls - 1) * CLS_STRIDE + rank] = sv;
        orig_c[(cls - 1) * CLS_STRIDE + rank] = order[tid];
    }
    if (tid == 0) {
        int tot = 0;
#pragma unroll
        for (int w = 0; w < 16; ++w) tot += wtot[w];
        counts[cls - 1] = tot < DET_PER_IMG ? tot : DET_PER_IMG;
    }
}

// ---------------- Kernel 2: global top-100 = 31-way merge, ONE wave ---------
// Lane c (c<31) owns class c's compacted sorted list. Key packs
// (positive-float score ‖ ~(c*128+r)) so u64max == (score desc, (c,r) asc),
// which equals the reference's flat-index tie order. No barriers at all.
__global__ __launch_bounds__(64) void topk_kernel(const float* __restrict__ scores_c,
                                                  const int* __restrict__ counts,
                                                  float* __restrict__ tk_score,
                                                  int* __restrict__ tk_idx) {
    const int lane = threadIdx.x;
    int cnt = (lane < 31) ? counts[lane] : 0;
    if (cnt > DET_PER_IMG) cnt = DET_PER_IMG;

    unsigned long long head = 0;
    if (lane < 31 && cnt > 0) {
        unsigned u = __float_as_uint(scores_c[lane * CLS_STRIDE]) | 0x80000000u;
        head = ((unsigned long long)u << 32) | (unsigned)~(lane << 7);
    }

    for (int it = 0; it < DET_PER_IMG; ++it) {
        unsigned long long wb = head;
#pragma unroll
        for (int off = 1; off < 64; off <<= 1)
            wb = u64max(wb, (unsigned long long)__shfl_xor((long long)wb, off));
        if (wb == 0) {            // exhausted: emit invalid
            if (lane == 0) { tk_score[it] = -1.0f; tk_idx[it] = 0; }
            continue;
        }
        unsigned v = ~(unsigned)wb;      // (c<<7)|r
        if (lane == 0) {
            tk_score[it] = __uint_as_float((unsigned)(wb >> 32) & 0x7fffffffu);
            tk_idx[it] = (int)v;
        }
        int c = (int)(v >> 7), r = (int)(v & 127);
        if (lane == c) {                 // winner's lane advances its list
            int pos = r + 1;
            head = 0;
            if (pos < cnt) {
                unsigned u = __float_as_uint(scores_c[lane * CLS_STRIDE + pos]) | 0x80000000u;
                head = ((unsigned long long)u << 32) | (unsigned)~((lane << 7) | pos);
            }
        }
    }
}

// ---------------- Kernel 3: gather outputs ----------------
// grid: DET_PER_IMG blocks of 256. Output layout (all float32):
// [100*4096 feats][100*6 boxes][100 scores][100 labels][100 valid]
__global__ void gather_kernel(const float* __restrict__ features,
                              const float* __restrict__ prop,
                              const float* __restrict__ reg,
                              const int* __restrict__ orig_c,
                              const float* __restrict__ tk_score,
                              const int* __restrict__ tk_idx,
                              float* __restrict__ out) {
    const int k = blockIdx.x;
    const int tid = threadIdx.x;
    float sc = tk_score[k];
    int flat = tk_idx[k];                 // (cls-1)*128 + rank
    bool valid = sc > 0.0f;
    int cls = (flat >> 7) + 1;
    int orig = valid ? orig_c[flat] : 0;

    // features row: 4096 floats = 1024 float4, vectorized copy
    const float4* src = (const float4*)(features + (size_t)orig * FEATD);
    float4* dstf = (float4*)(out + (size_t)k * FEATD);
    const float4 z4 = make_float4(0.f, 0.f, 0.f, 0.f);
#pragma unroll
    for (int t = 0; t < 4; ++t) {
        int idx = tid + t * 256;
        dstf[idx] = valid ? src[idx] : z4;
    }

    const size_t boxOff = (size_t)DET_PER_IMG * FEATD;
    if (tid == 0) {
        float bb[6];
        decode_box(prop, reg, orig, cls, bb);   // bit-equivalent re-decode
#pragma unroll
        for (int d = 0; d < 6; ++d)
            out[boxOff + k * 6 + d] = valid ? bb[d] : 0.0f;
    }
    if (tid == 1) out[boxOff + 600 + k] = valid ? sc : 0.0f;
    if (tid == 2) out[boxOff + 700 + k] = valid ? (float)cls : 0.0f;
    if (tid == 3) out[boxOff + 800 + k] = valid ? 1.0f : 0.0f;
}

extern "C" void kernel_launch(void* const* d_in, const int* in_sizes, int n_in,
                              void* d_out, int out_size, void* d_ws, size_t ws_size,
                              hipStream_t stream) {
    (void)in_sizes; (void)n_in; (void)out_size; (void)ws_size;
    const float* features = (const float*)d_in[0];   // [1024,4096]
    const float* logits   = (const float*)d_in[1];   // [1024,32]
    const float* reg      = (const float*)d_in[2];   // [1024,192]
    const float* prop     = (const float*)d_in[3];   // [1024,6]
    float* out = (float*)d_out;

    // workspace layout (floats/ints, all 4-byte aligned)
    float* scores_c = (float*)d_ws;                       // 31*128 = 3968
    int*   orig_c   = (int*)(scores_c + 31 * CLS_STRIDE); // 3968
    int*   counts   = (int*)(orig_c + 31 * CLS_STRIDE);   // 31 (+1 pad)
    float* tk_score = (float*)(counts + 32);              // 100
    int*   tk_idx   = (int*)(tk_score + DET_PER_IMG);     // 100

    nms_kernel<<<NCLS - 1, 1024, 0, stream>>>(logits, reg, prop,
                                              scores_c, orig_c, counts);
    topk_kernel<<<1, 64, 0, stream>>>(scores_c, counts, tk_score, tk_idx);
    gather_kernel<<<DET_PER_IMG, 256, 0, stream>>>(
        features, prop, reg, orig_c, tk_score, tk_idx, out);
}

// Round 12
// 172.673 us; speedup vs baseline: 3.3186x; 1.0213x over previous
//
#include <hip/hip_runtime.h>
#include <math.h>

#define NPROP 1024
#define NCLS 32
#define FEATD 4096
#define SCORE_THRESH 0.05f
#define NMS_THR 0.5f
#define DET_PER_IMG 100
#define CLS_STRIDE 128            // per-class compacted list stride (>=100)
#define BBOX_CLIP 4.135166556742356f   // log(1000/16)

__device__ __forceinline__ unsigned long long u64max(unsigned long long a,
                                                     unsigned long long b) {
    return a > b ? a : b;
}

// monotone float -> uint map (order-preserving for all finite floats)
__device__ __forceinline__ unsigned flip_f32(float f) {
    unsigned u = __float_as_uint(f);
    return u ^ ((unsigned)(((int)u) >> 31) | 0x80000000u);
}
__device__ __forceinline__ float unflip_f32(unsigned u) {
    u = (u & 0x80000000u) ? (u ^ 0x80000000u) : ~u;
    return __uint_as_float(u);
}

__device__ __forceinline__ unsigned long long shfl_xor_u64(unsigned long long v,
                                                           int mask) {
    return (unsigned long long)__shfl_xor((long long)v, mask);
}

// Box decode + clip for proposal n, class cls. zyxzyx, TO_REMOVE=1 convention.
// __fmul_rn/__fadd_rn block FMA contraction so coords match XLA's unfused
// mul+add (IoU>thr and score>thresh are discrete decisions). b[] is only
// indexed with compile-time constants (rule #20).
__device__ __forceinline__ void decode_box(const float* __restrict__ prop,
                                           const float* __restrict__ reg,
                                           int n, int cls, float b[6]) {
    const float lim[3] = {95.0f, 319.0f, 319.0f};
    const float* r6 = reg + n * (NCLS * 6) + cls * 6;
#pragma unroll
    for (int d = 0; d < 3; ++d) {
        float lo = prop[n * 6 + d];
        float hi = prop[n * 6 + 3 + d];
        float sz = __fadd_rn(__fsub_rn(hi, lo), 1.0f);
        float ct = __fadd_rn(lo, __fmul_rn(0.5f, sz));
        float dc = r6[d] / 10.0f;                       // W_CTR = 10
        float ds = fminf(r6[3 + d] / 5.0f, BBOX_CLIP);  // W_SIZE = 5
        float pc = __fadd_rn(__fmul_rn(dc, sz), ct);
        float ps = __fmul_rn(expf(ds), sz);
        float hps = __fmul_rn(0.5f, ps);
        float mn = __fsub_rn(pc, hps);
        float mx = __fsub_rn(__fadd_rn(pc, hps), 1.0f);
        b[d]     = fminf(fmaxf(mn, 0.0f), lim[d]);
        b[3 + d] = fminf(fmaxf(mx, 0.0f), lim[d]);
    }
}

// ---------------- Kernel 1: softmax + decode + sort + windowed NMS ----------
// grid: 31 blocks (class = blockIdx.x+1) of 1024 threads.
// Emits per-class compacted sorted kept list (rank<100) + count.
__global__ __launch_bounds__(1024) void nms_kernel(const float* __restrict__ logits,
                                                   const float* __restrict__ reg,
                                                   const float* __restrict__ prop,
                                                   float* __restrict__ scores_c,
                                                   int* __restrict__ orig_c,
                                                   int* __restrict__ counts) {
    const int cls = blockIdx.x + 1;   // foreground classes 1..31
    const int tid = threadIdx.x;
    const int lane = tid & 63, wid = tid >> 6;

    __shared__ unsigned long long kbuf[2][NPROP];   // 16 KB, sort ping-pong
    __shared__ float sb[NPROP][6];                  // 24 KB
    __shared__ float vols[NPROP];                   // 4 KB
    __shared__ unsigned long long keepw[16];
    __shared__ int   wtot[16];
    __shared__ int   kept_cum[2];   // parity-buffered running kept count

    // --- inline softmax for this thread's own proposal row (static indexing) ---
    const float* lrow = logits + tid * NCLS;
    float4 q[8];
#pragma unroll
    for (int r = 0; r < 8; ++r) q[r] = ((const float4*)lrow)[r];
    float m = -1e30f;
#pragma unroll
    for (int r = 0; r < 8; ++r)
        m = fmaxf(m, fmaxf(fmaxf(q[r].x, q[r].y), fmaxf(q[r].z, q[r].w)));
    float ssum = 0.0f;
#pragma unroll
    for (int r = 0; r < 8; ++r) {
        ssum += expf(q[r].x - m);
        ssum += expf(q[r].y - m);
        ssum += expf(q[r].z - m);
        ssum += expf(q[r].w - m);
    }
    float xc = lrow[cls];            // scalar load; q[cls] would spill (rule #20)
    float p = expf(xc - m) / ssum;
    float sv0 = (p > SCORE_THRESH) ? p : -1.0f;

    // --- hybrid bitonic sort on packed u64 keys, DESCENDING ---
    // key = (flip(score) << 32) | ~idx  =>  u64 desc == (score desc, idx asc),
    // exactly jnp.argsort(-s)'s stable order. Thread t owns position t; j<64
    // steps are pure register shuffles (no LDS, no barrier); j>=64 steps go
    // through a ping-pong LDS buffer with ONE barrier each (WAR-safe: next
    // cross-wave step writes the other buffer, and its barrier orders the
    // previous buffer's reads before any re-write two steps later).
    unsigned long long key =
        ((unsigned long long)flip_f32(sv0) << 32) | (unsigned)~tid;
    int pb = 0;
    for (int k = 2; k <= NPROP; k <<= 1) {
        for (int j = k >> 1; j > 0; j >>= 1) {
            unsigned long long pk;
            if (j >= 64) {
                kbuf[pb][tid] = key;
                __syncthreads();
                pk = kbuf[pb][tid ^ j];
                pb ^= 1;
            } else {
                pk = shfl_xor_u64(key, j);
            }
            bool lower = (tid & j) == 0;
            bool desc  = (tid & k) == 0;
            bool want_max = (lower == desc);
            bool pk_gt = pk > key;
            key = (want_max == pk_gt) ? pk : key;
        }
    }
    // recover sorted (score, original idx) from key — all in registers
    float sv = unflip_f32((unsigned)(key >> 32));
    int o = (int)(~(unsigned)key);

    // Decode this thread's sorted box inline; stage to LDS
    float myb[6];
    decode_box(prop, reg, o, cls, myb);
#pragma unroll
    for (int d = 0; d < 6; ++d) sb[tid][d] = myb[d];
    float myvol = 1.0f;
#pragma unroll
    for (int d = 0; d < 3; ++d)
        myvol *= fmaxf(myb[3 + d] - myb[d] + 1.0f, 0.0f);
    vols[tid] = myvol;

    int mykeep = (sv > SCORE_THRESH) ? 1 : 0;
    unsigned long long m0 = __ballot(mykeep);
    if (lane == 0) keepw[wid] = m0;
    if (tid == 0) { kept_cum[0] = 0; kept_cum[1] = 0; }
    __syncthreads();

    // Windowed greedy NMS: 16 windows of 64 sorted boxes. Each round, every
    // wave with wid>=w redundantly resolves window w's intra-window greedy
    // suppression in-register (identical result in all waves), then applies
    // the window's final kept set to its own later boxes. One barrier/round.
    // Early-stop once >=100 kept (later kept boxes get rank>=100, never
    // emitted; suppression only flows forward so earlier ranks are final).
    for (int w = 0; w < 16; ++w) {
        if (kept_cum[w & 1] >= DET_PER_IMG) break;   // uniform (post-barrier)
        unsigned long long wk = 0;
        if (wid >= w) {
            wk = keepw[w];
            const int base = w << 6;
            if (wk) {
                // my lane's window box (banks: stride 6 -> 2-way alias, free)
                float w0 = sb[base + lane][0], w1 = sb[base + lane][1];
                float w2 = sb[base + lane][2], w3 = sb[base + lane][3];
                float w4 = sb[base + lane][4], w5 = sb[base + lane][5];
                float wv = vols[base + lane];
                unsigned long long rest = wk;
                while (rest) {
                    int b = __ffsll((long long)rest) - 1;
                    rest &= rest - 1;
                    float b0 = sb[base + b][0], b1 = sb[base + b][1];
                    float b2 = sb[base + b][2], b3 = sb[base + b][3];
                    float b4 = sb[base + b][4], b5 = sb[base + b][5];
                    float bv = vols[base + b];
                    bool sup = false;
                    if (lane > b && ((wk >> lane) & 1)) {
                        float i0 = fmaxf(fminf(w3, b3) - fmaxf(w0, b0) + 1.0f, 0.0f);
                        float i1 = fmaxf(fminf(w4, b4) - fmaxf(w1, b1) + 1.0f, 0.0f);
                        float i2 = fmaxf(fminf(w5, b5) - fmaxf(w2, b2) + 1.0f, 0.0f);
                        float inter = i0 * i1 * i2;
                        sup = inter / (bv + wv - inter + 1e-12f) > NMS_THR;
                    }
                    unsigned long long supm = __ballot(sup);
                    wk &= ~supm;
                    rest &= ~supm;
                }
                if (wid == w) {
                    mykeep = (int)((wk >> lane) & 1);
                } else if (mykeep) {
                    // apply window's kept set to my (later) box
                    unsigned long long t = wk;
                    while (t) {
                        int bb = __ffsll((long long)t) - 1;
                        t &= t - 1;
                        float b0 = sb[base + bb][0], b1 = sb[base + bb][1];
                        float b2 = sb[base + bb][2], b3 = sb[base + bb][3];
                        float b4 = sb[base + bb][4], b5 = sb[base + bb][5];
                        float bv = vols[base + bb];
                        float i0 = fmaxf(fminf(myb[3], b3) - fmaxf(myb[0], b0) + 1.0f, 0.0f);
                        float i1 = fmaxf(fminf(myb[4], b4) - fmaxf(myb[1], b1) + 1.0f, 0.0f);
                        float i2 = fmaxf(fminf(myb[5], b5) - fmaxf(myb[2], b2) + 1.0f, 0.0f);
                        float inter = i0 * i1 * i2;
                        if (inter / (bv + myvol - inter + 1e-12f) > NMS_THR) {
                            mykeep = 0;
                            break;
                        }
                    }
                }
            }
            if (wid == w && lane == 0)
                kept_cum[(w + 1) & 1] = kept_cum[w & 1] + __popcll(wk);
        }
        unsigned long long mm = __ballot(mykeep);
        if (lane == 0) keepw[wid] = mm;
        __syncthreads();
    }

    // rank = exclusive prefix count of keep; emit rank < 100 compacted
    unsigned long long mask = __ballot(mykeep);
    int pre = __popcll(mask & ((1ull << lane) - 1ull));
    if (lane == 0) wtot[wid] = __popcll(mask);
    __syncthreads();
    int before = 0;
    for (int w = 0; w < wid; ++w) before += wtot[w];
    int rank = before + pre;

    if (mykeep && rank < DET_PER_IMG) {
        scores_c[(cls - 1) * CLS_STRIDE + rank] = sv;
        orig_c[(cls - 1) * CLS_STRIDE + rank] = o;
    }
    if (tid == 0) {
        int tot = 0;
#pragma unroll
        for (int w = 0; w < 16; ++w) tot += wtot[w];
        counts[cls - 1] = tot < DET_PER_IMG ? tot : DET_PER_IMG;
    }
}

// ---------------- Kernel 2: global top-100 = 31-way merge, ONE wave ---------
// Lane c (c<31) owns class c's compacted sorted list, STAGED IN LDS (15.5 KB)
// so the per-iteration advance is an LDS read, not a cross-XCD global load.
// Key packs (positive-float score ‖ ~(c*128+r)) so u64max == (score desc,
// (c,r) asc), which equals the reference's flat-index tie order. No barriers
// in the merge loop (single wave).
__global__ __launch_bounds__(64) void topk_kernel(const float* __restrict__ scores_c,
                                                  const int* __restrict__ counts,
                                                  float* __restrict__ tk_score,
                                                  int* __restrict__ tk_idx) {
    const int lane = threadIdx.x;
    __shared__ float lsc[31 * CLS_STRIDE];          // 15.5 KB

    // coalesced bulk stage: 31*128 floats = 992 float4
    const float4* src4 = (const float4*)scores_c;
    float4* dst4 = (float4*)lsc;
#pragma unroll
    for (int t = 0; t < 16; ++t) {
        int idx = t * 64 + lane;
        if (idx < (31 * CLS_STRIDE) / 4) dst4[idx] = src4[idx];
    }
    int cnt = (lane < 31) ? counts[lane] : 0;
    if (cnt > DET_PER_IMG) cnt = DET_PER_IMG;
    __syncthreads();

    unsigned long long head = 0;
    if (lane < 31 && cnt > 0) {
        unsigned u = __float_as_uint(lsc[lane * CLS_STRIDE]) | 0x80000000u;
        head = ((unsigned long long)u << 32) | (unsigned)~(lane << 7);
    }

    for (int it = 0; it < DET_PER_IMG; ++it) {
        unsigned long long wb = head;
#pragma unroll
        for (int off = 1; off < 64; off <<= 1)
            wb = u64max(wb, shfl_xor_u64(wb, off));
        if (wb == 0) {            // exhausted: emit invalid
            if (lane == 0) { tk_score[it] = -1.0f; tk_idx[it] = 0; }
            continue;
        }
        unsigned v = ~(unsigned)wb;      // (c<<7)|r
        if (lane == 0) {
            tk_score[it] = __uint_as_float((unsigned)(wb >> 32) & 0x7fffffffu);
            tk_idx[it] = (int)v;
        }
        int c = (int)(v >> 7), r = (int)(v & 127);
        if (lane == c) {                 // winner's lane advances its list
            int pos = r + 1;
            head = 0;
            if (pos < cnt) {
                unsigned u = __float_as_uint(lsc[lane * CLS_STRIDE + pos]) | 0x80000000u;
                head = ((unsigned long long)u << 32) | (unsigned)~((lane << 7) | pos);
            }
        }
    }
}

// ---------------- Kernel 3: gather outputs ----------------
// grid: DET_PER_IMG blocks of 256. Output layout (all float32):
// [100*4096 feats][100*6 boxes][100 scores][100 labels][100 valid]
__global__ void gather_kernel(const float* __restrict__ features,
                              const float* __restrict__ prop,
                              const float* __restrict__ reg,
                              const int* __restrict__ orig_c,
                              const float* __restrict__ tk_score,
                              const int* __restrict__ tk_idx,
                              float* __restrict__ out) {
    const int k = blockIdx.x;
    const int tid = threadIdx.x;
    float sc = tk_score[k];
    int flat = tk_idx[k];                 // (cls-1)*128 + rank
    bool valid = sc > 0.0f;
    int cls = (flat >> 7) + 1;
    int orig = valid ? orig_c[flat] : 0;

    // features row: 4096 floats = 1024 float4, vectorized copy
    const float4* src = (const float4*)(features + (size_t)orig * FEATD);
    float4* dstf = (float4*)(out + (size_t)k * FEATD);
    const float4 z4 = make_float4(0.f, 0.f, 0.f, 0.f);
#pragma unroll
    for (int t = 0; t < 4; ++t) {
        int idx = tid + t * 256;
        dstf[idx] = valid ? src[idx] : z4;
    }

    const size_t boxOff = (size_t)DET_PER_IMG * FEATD;
    if (tid == 0) {
        float bb[6];
        decode_box(prop, reg, orig, cls, bb);   // bit-equivalent re-decode
#pragma unroll
        for (int d = 0; d < 6; ++d)
            out[boxOff + k * 6 + d] = valid ? bb[d] : 0.0f;
    }
    if (tid == 1) out[boxOff + 600 + k] = valid ? sc : 0.0f;
    if (tid == 2) out[boxOff + 700 + k] = valid ? (float)cls : 0.0f;
    if (tid == 3) out[boxOff + 800 + k] = valid ? 1.0f : 0.0f;
}

extern "C" void kernel_launch(void* const* d_in, const int* in_sizes, int n_in,
                              void* d_out, int out_size, void* d_ws, size_t ws_size,
                              hipStream_t stream) {
    (void)in_sizes; (void)n_in; (void)out_size; (void)ws_size;
    const float* features = (const float*)d_in[0];   // [1024,4096]
    const float* logits   = (const float*)d_in[1];   // [1024,32]
    const float* reg      = (const float*)d_in[2];   // [1024,192]
    const float* prop     = (const float*)d_in[3];   // [1024,6]
    float* out = (float*)d_out;

    // workspace layout (floats/ints, all 4-byte aligned)
    float* scores_c = (float*)d_ws;                       // 31*128 = 3968
    int*   orig_c   = (int*)(scores_c + 31 * CLS_STRIDE); // 3968
    int*   counts   = (int*)(orig_c + 31 * CLS_STRIDE);   // 31 (+1 pad)
    float* tk_score = (float*)(counts + 32);              // 100
    int*   tk_idx   = (int*)(tk_score + DET_PER_IMG);     // 100

    nms_kernel<<<NCLS - 1, 1024, 0, stream>>>(logits, reg, prop,
                                              scores_c, orig_c, counts);
    topk_kernel<<<1, 64, 0, stream>>>(scores_c, counts, tk_score, tk_idx);
    gather_kernel<<<DET_PER_IMG, 256, 0, stream>>>(
        features, prop, reg, orig_c, tk_score, tk_idx, out);
}

// Round 13
// 169.723 us; speedup vs baseline: 3.3763x; 1.0174x over previous
//
#include <hip/hip_runtime.h>
#include <math.h>

#define NPROP 1024
#define NCLS 32
#define FEATD 4096
#define SCORE_THRESH 0.05f
#define NMS_THR 0.5f
#define DET_PER_IMG 100
#define CLS_STRIDE 128            // per-class compacted list stride (>=100)
#define BBOX_CLIP 4.135166556742356f   // log(1000/16)

__device__ __forceinline__ unsigned long long u64max(unsigned long long a,
                                                     unsigned long long b) {
    return a > b ? a : b;
}

// monotone float -> uint map (order-preserving for all finite floats)
__device__ __forceinline__ unsigned flip_f32(float f) {
    unsigned u = __float_as_uint(f);
    return u ^ ((unsigned)(((int)u) >> 31) | 0x80000000u);
}
__device__ __forceinline__ float unflip_f32(unsigned u) {
    u = (u & 0x80000000u) ? (u ^ 0x80000000u) : ~u;
    return __uint_as_float(u);
}

__device__ __forceinline__ unsigned long long shfl_xor_u64(unsigned long long v,
                                                           int mask) {
    return (unsigned long long)__shfl_xor((long long)v, mask);
}
__device__ __forceinline__ unsigned long long shfl_xor_u64_w32(unsigned long long v,
                                                               int mask) {
    return (unsigned long long)__shfl_xor((long long)v, mask, 32);
}

// wave-uniform broadcast of lane `l`'s value via v_readlane (VALU pipe, NOT the
// LDS pipe — ds_bpermute/ds_read broadcasts all serialize on the CU's single
// LDS pipe, which was the r12 bottleneck).
__device__ __forceinline__ float readlane_f32(float v, int l) {
    return __uint_as_float((unsigned)__builtin_amdgcn_readlane(__float_as_uint(v), l));
}

// Box decode + clip for proposal n, class cls. zyxzyx, TO_REMOVE=1 convention.
// __fmul_rn/__fadd_rn block FMA contraction so coords match XLA's unfused
// mul+add (IoU>thr and score>thresh are discrete decisions). b[] is only
// indexed with compile-time constants (rule #20).
__device__ __forceinline__ void decode_box(const float* __restrict__ prop,
                                           const float* __restrict__ reg,
                                           int n, int cls, float b[6]) {
    const float lim[3] = {95.0f, 319.0f, 319.0f};
    const float* r6 = reg + n * (NCLS * 6) + cls * 6;
#pragma unroll
    for (int d = 0; d < 3; ++d) {
        float lo = prop[n * 6 + d];
        float hi = prop[n * 6 + 3 + d];
        float sz = __fadd_rn(__fsub_rn(hi, lo), 1.0f);
        float ct = __fadd_rn(lo, __fmul_rn(0.5f, sz));
        float dc = r6[d] / 10.0f;                       // W_CTR = 10
        float ds = fminf(r6[3 + d] / 5.0f, BBOX_CLIP);  // W_SIZE = 5
        float pc = __fadd_rn(__fmul_rn(dc, sz), ct);
        float ps = __fmul_rn(expf(ds), sz);
        float hps = __fmul_rn(0.5f, ps);
        float mn = __fsub_rn(pc, hps);
        float mx = __fsub_rn(__fadd_rn(pc, hps), 1.0f);
        b[d]     = fminf(fmaxf(mn, 0.0f), lim[d]);
        b[3 + d] = fminf(fmaxf(mx, 0.0f), lim[d]);
    }
}

// ---------------- Kernel 1: softmax + decode + sort + windowed NMS ----------
// grid: 31 blocks (class = blockIdx.x+1) of 1024 threads.
// Emits per-class compacted sorted kept list (rank<100) + count.
__global__ __launch_bounds__(1024) void nms_kernel(const float* __restrict__ logits,
                                                   const float* __restrict__ reg,
                                                   const float* __restrict__ prop,
                                                   float* __restrict__ scores_c,
                                                   int* __restrict__ orig_c,
                                                   int* __restrict__ counts) {
    const int cls = blockIdx.x + 1;   // foreground classes 1..31
    const int tid = threadIdx.x;
    const int lane = tid & 63, wid = tid >> 6;

    __shared__ unsigned long long kbuf[2][NPROP];   // 16 KB, sort ping-pong
    __shared__ float sbv[NPROP][7];                 // 28 KB: 6 coords + vol, pad 7
    __shared__ unsigned long long keepw[16];
    __shared__ int   wtot[16];
    __shared__ int   wvalid[16];
    __shared__ int   kept_cum[2];   // parity-buffered running kept count

    // --- inline softmax for this thread's own proposal row (static indexing) ---
    const float* lrow = logits + tid * NCLS;
    float4 q[8];
#pragma unroll
    for (int r = 0; r < 8; ++r) q[r] = ((const float4*)lrow)[r];
    float m = -1e30f;
#pragma unroll
    for (int r = 0; r < 8; ++r)
        m = fmaxf(m, fmaxf(fmaxf(q[r].x, q[r].y), fmaxf(q[r].z, q[r].w)));
    float ssum = 0.0f;
#pragma unroll
    for (int r = 0; r < 8; ++r) {
        ssum += expf(q[r].x - m);
        ssum += expf(q[r].y - m);
        ssum += expf(q[r].z - m);
        ssum += expf(q[r].w - m);
    }
    float xc = lrow[cls];            // scalar load; q[cls] would spill (rule #20)
    float p = expf(xc - m) / ssum;
    float sv0 = (p > SCORE_THRESH) ? p : -1.0f;

    // --- hybrid bitonic sort on packed u64 keys, DESCENDING ---
    // key = (flip(score) << 32) | ~idx  =>  u64 desc == (score desc, idx asc),
    // exactly jnp.argsort(-s)'s stable order. j<64 steps: register shuffles;
    // j>=64: ping-pong LDS with one barrier each (WAR-safe: re-write of a
    // buffer is separated from its reads by the intervening step's barrier).
    unsigned long long key =
        ((unsigned long long)flip_f32(sv0) << 32) | (unsigned)~tid;
    int pb = 0;
    for (int k = 2; k <= NPROP; k <<= 1) {
        for (int j = k >> 1; j > 0; j >>= 1) {
            unsigned long long pk;
            if (j >= 64) {
                kbuf[pb][tid] = key;
                __syncthreads();
                pk = kbuf[pb][tid ^ j];
                pb ^= 1;
            } else {
                pk = shfl_xor_u64(key, j);
            }
            bool lower = (tid & j) == 0;
            bool desc  = (tid & k) == 0;
            bool want_max = (lower == desc);
            bool pk_gt = pk > key;
            key = (want_max == pk_gt) ? pk : key;
        }
    }
    // recover sorted (score, original idx) from key — all in registers
    float sv = unflip_f32((unsigned)(key >> 32));
    int o = (int)(~(unsigned)key);

    // Decode this thread's sorted box inline; stage coords+vol to LDS (pad 7)
    float myb[6];
    decode_box(prop, reg, o, cls, myb);
#pragma unroll
    for (int d = 0; d < 6; ++d) sbv[tid][d] = myb[d];
    float myvol = 1.0f;
#pragma unroll
    for (int d = 0; d < 3; ++d)
        myvol *= fmaxf(myb[3 + d] - myb[d] + 1.0f, 0.0f);
    sbv[tid][6] = myvol;

    int mykeep = (sv > SCORE_THRESH) ? 1 : 0;
    unsigned long long vb = __ballot(mykeep);
    if (lane == 0) wvalid[wid] = __popcll(vb);
    if (tid == 0) { kept_cum[0] = 0; kept_cum[1] = 0; }
    __syncthreads();

    // valid boxes are a sorted PREFIX -> only ceil(nv/64) windows are nonempty
    int nv = 0;
#pragma unroll
    for (int w = 0; w < 16; ++w) nv += wvalid[w];
    int nrounds = (nv + 63) >> 6;

    // Windowed greedy NMS, register/readlane edition. Per round w:
    //   phase A: wave w alone resolves window w's intra-window greedy
    //            suppression (its boxes ARE its myb registers; broadcasts via
    //            v_readlane on the VALU pipe — no LDS traffic).
    //   barrier; phase B: waves > w with any kept box load window w's boxes
    //            into 7 registers (one conflict-free LDS pass) and test their
    //            own boxes against the kept set via readlane broadcasts.
    // Early-stop when resolved kept >= 100 (later boxes can never be emitted;
    // suppression only flows forward so earlier ranks are final).
    for (int w = 0; w < nrounds; ++w) {
        if (kept_cum[w & 1] >= DET_PER_IMG) break;   // uniform (post-barrier)
        const int base = w << 6;

        if (wid == w) {
            // resolve window w in-register
            unsigned long long wk = __ballot(mykeep);
            unsigned long long rest = wk;
            while (rest) {
                int b = __ffsll((long long)rest) - 1;
                rest &= rest - 1;
                float b0 = readlane_f32(myb[0], b), b1 = readlane_f32(myb[1], b);
                float b2 = readlane_f32(myb[2], b), b3 = readlane_f32(myb[3], b);
                float b4 = readlane_f32(myb[4], b), b5 = readlane_f32(myb[5], b);
                float bv = readlane_f32(myvol, b);
                bool sup = false;
                if (lane > b && ((wk >> lane) & 1)) {
                    float i0 = fmaxf(fminf(myb[3], b3) - fmaxf(myb[0], b0) + 1.0f, 0.0f);
                    float i1 = fmaxf(fminf(myb[4], b4) - fmaxf(myb[1], b1) + 1.0f, 0.0f);
                    float i2 = fmaxf(fminf(myb[5], b5) - fmaxf(myb[2], b2) + 1.0f, 0.0f);
                    float inter = i0 * i1 * i2;
                    sup = inter / (bv + myvol - inter + 1e-12f) > NMS_THR;
                }
                unsigned long long sm = __ballot(sup);
                wk &= ~sm;
                rest &= ~sm;
            }
            mykeep = (int)((wk >> lane) & 1);
            if (lane == 0) {
                keepw[w] = wk;
                kept_cum[(w + 1) & 1] = kept_cum[w & 1] + __popcll(wk);
            }
        }
        __syncthreads();

        unsigned long long wkf = keepw[w];
        bool anyk = __ballot(mykeep) != 0;   // wave-uniform
        if (wid > w && anyk && wkf) {
            // load window w's boxes into registers (stride-7 -> 2-way, free)
            float r0 = sbv[base + lane][0], r1 = sbv[base + lane][1];
            float r2 = sbv[base + lane][2], r3 = sbv[base + lane][3];
            float r4 = sbv[base + lane][4], r5 = sbv[base + lane][5];
            float rv = sbv[base + lane][6];
            if (mykeep) {
                unsigned long long t = wkf;
                while (t) {
                    int bb = __ffsll((long long)t) - 1;
                    t &= t - 1;
                    float b0 = readlane_f32(r0, bb), b1 = readlane_f32(r1, bb);
                    float b2 = readlane_f32(r2, bb), b3 = readlane_f32(r3, bb);
                    float b4 = readlane_f32(r4, bb), b5 = readlane_f32(r5, bb);
                    float bv = readlane_f32(rv, bb);
                    float i0 = fmaxf(fminf(myb[3], b3) - fmaxf(myb[0], b0) + 1.0f, 0.0f);
                    float i1 = fmaxf(fminf(myb[4], b4) - fmaxf(myb[1], b1) + 1.0f, 0.0f);
                    float i2 = fmaxf(fminf(myb[5], b5) - fmaxf(myb[2], b2) + 1.0f, 0.0f);
                    float inter = i0 * i1 * i2;
                    if (inter / (bv + myvol - inter + 1e-12f) > NMS_THR) {
                        mykeep = 0;
                        break;
                    }
                }
            }
        }
        __syncthreads();
    }

    // rank = exclusive prefix count of keep; emit rank < 100 compacted
    unsigned long long mask = __ballot(mykeep);
    int pre = __popcll(mask & ((1ull << lane) - 1ull));
    if (lane == 0) wtot[wid] = __popcll(mask);
    __syncthreads();
    int before = 0;
    for (int w = 0; w < wid; ++w) before += wtot[w];
    int rank = before + pre;

    if (mykeep && rank < DET_PER_IMG) {
        scores_c[(cls - 1) * CLS_STRIDE + rank] = sv;
        orig_c[(cls - 1) * CLS_STRIDE + rank] = o;
    }
    if (tid == 0) {
        int tot = 0;
#pragma unroll
        for (int w = 0; w < 16; ++w) tot += wtot[w];
        counts[cls - 1] = tot < DET_PER_IMG ? tot : DET_PER_IMG;
    }
}

// ---------------- Kernel 2: global top-100 = 31-way merge, ONE wave ---------
// Lane c (c<31) owns class c's compacted sorted list, staged in LDS. Each lane
// holds head AND next (prefetched) as registers, so the winner-advance is a
// register swap and the refill LDS read overlaps the next reduction rounds —
// the per-iteration critical path is just the 5-step width-32 u64 reduce.
// Key packs (positive-float score ‖ ~(c*128+r)) so u64max == (score desc,
// (c,r) asc) == the reference's flat-index tie order.
__global__ __launch_bounds__(64) void topk_kernel(const float* __restrict__ scores_c,
                                                  const int* __restrict__ counts,
                                                  float* __restrict__ tk_score,
                                                  int* __restrict__ tk_idx) {
    const int lane = threadIdx.x;
    __shared__ float lsc[31 * CLS_STRIDE];          // 15.5 KB

    // coalesced bulk stage: 31*128 floats = 992 float4
    const float4* src4 = (const float4*)scores_c;
    float4* dst4 = (float4*)lsc;
#pragma unroll
    for (int t = 0; t < 16; ++t) {
        int idx = t * 64 + lane;
        if (idx < (31 * CLS_STRIDE) / 4) dst4[idx] = src4[idx];
    }
    int cnt = (lane < 31) ? counts[lane] : 0;
    if (cnt > DET_PER_IMG) cnt = DET_PER_IMG;
    __syncthreads();

    int pos = 0;
    unsigned long long head = 0, nxt = 0;
    if (lane < 31) {
        if (cnt > 0) {
            unsigned u = __float_as_uint(lsc[lane * CLS_STRIDE]) | 0x80000000u;
            head = ((unsigned long long)u << 32) | (unsigned)~(lane << 7);
        }
        if (cnt > 1) {
            unsigned u = __float_as_uint(lsc[lane * CLS_STRIDE + 1]) | 0x80000000u;
            nxt = ((unsigned long long)u << 32) | (unsigned)~((lane << 7) | 1);
        }
    }

    for (int it = 0; it < DET_PER_IMG; ++it) {
        unsigned long long wb = head;
#pragma unroll
        for (int off = 1; off < 32; off <<= 1)
            wb = u64max(wb, shfl_xor_u64_w32(wb, off));
        if (wb == 0) {            // exhausted: emit invalid
            if (lane == 0) { tk_score[it] = -1.0f; tk_idx[it] = 0; }
            continue;
        }
        unsigned v = ~(unsigned)wb;      // (c<<7)|r
        if (lane == 0) {
            tk_score[it] = __uint_as_float((unsigned)(wb >> 32) & 0x7fffffffu);
            tk_idx[it] = (int)v;
        }
        int c = (int)(v >> 7);
        if (lane == c) {                 // winner's lane advances (prefetched)
            ++pos;
            head = nxt;
            int p2 = pos + 1;
            nxt = 0;
            if (p2 < cnt) {
                unsigned u = __float_as_uint(lsc[lane * CLS_STRIDE + p2]) | 0x80000000u;
                nxt = ((unsigned long long)u << 32) | (unsigned)~((lane << 7) | p2);
            }
        }
    }
}

// ---------------- Kernel 3: gather outputs ----------------
// grid: DET_PER_IMG blocks of 256. Output layout (all float32):
// [100*4096 feats][100*6 boxes][100 scores][100 labels][100 valid]
__global__ void gather_kernel(const float* __restrict__ features,
                              const float* __restrict__ prop,
                              const float* __restrict__ reg,
                              const int* __restrict__ orig_c,
                              const float* __restrict__ tk_score,
                              const int* __restrict__ tk_idx,
                              float* __restrict__ out) {
    const int k = blockIdx.x;
    const int tid = threadIdx.x;
    float sc = tk_score[k];
    int flat = tk_idx[k];                 // (cls-1)*128 + rank
    bool valid = sc > 0.0f;
    int cls = (flat >> 7) + 1;
    int orig = valid ? orig_c[flat] : 0;

    // features row: 4096 floats = 1024 float4, vectorized copy
    const float4* src = (const float4*)(features + (size_t)orig * FEATD);
    float4* dstf = (float4*)(out + (size_t)k * FEATD);
    const float4 z4 = make_float4(0.f, 0.f, 0.f, 0.f);
#pragma unroll
    for (int t = 0; t < 4; ++t) {
        int idx = tid + t * 256;
        dstf[idx] = valid ? src[idx] : z4;
    }

    const size_t boxOff = (size_t)DET_PER_IMG * FEATD;
    if (tid == 0) {
        float bb[6];
        decode_box(prop, reg, orig, cls, bb);   // bit-equivalent re-decode
#pragma unroll
        for (int d = 0; d < 6; ++d)
            out[boxOff + k * 6 + d] = valid ? bb[d] : 0.0f;
    }
    if (tid == 1) out[boxOff + 600 + k] = valid ? sc : 0.0f;
    if (tid == 2) out[boxOff + 700 + k] = valid ? (float)cls : 0.0f;
    if (tid == 3) out[boxOff + 800 + k] = valid ? 1.0f : 0.0f;
}

extern "C" void kernel_launch(void* const* d_in, const int* in_sizes, int n_in,
                              void* d_out, int out_size, void* d_ws, size_t ws_size,
                              hipStream_t stream) {
    (void)in_sizes; (void)n_in; (void)out_size; (void)ws_size;
    const float* features = (const float*)d_in[0];   // [1024,4096]
    const float* logits   = (const float*)d_in[1];   // [1024,32]
    const float* reg      = (const float*)d_in[2];   // [1024,192]
    const float* prop     = (const float*)d_in[3];   // [1024,6]
    float* out = (float*)d_out;

    // workspace layout (floats/ints, all 4-byte aligned)
    float* scores_c = (float*)d_ws;                       // 31*128 = 3968
    int*   orig_c   = (int*)(scores_c + 31 * CLS_STRIDE); // 3968
    int*   counts   = (int*)(orig_c + 31 * CLS_STRIDE);   // 31 (+1 pad)
    float* tk_score = (float*)(counts + 32);              // 100
    int*   tk_idx   = (int*)(tk_score + DET_PER_IMG);     // 100

    nms_kernel<<<NCLS - 1, 1024, 0, stream>>>(logits, reg, prop,
                                              scores_c, orig_c, counts);
    topk_kernel<<<1, 64, 0, stream>>>(scores_c, counts, tk_score, tk_idx);
    gather_kernel<<<DET_PER_IMG, 256, 0, stream>>>(
        features, prop, reg, orig_c, tk_score, tk_idx, out);
}